// Round 4
// baseline (212.395 us; speedup 1.0000x reference)
//
#include <hip/hip_runtime.h>

#define NMODELS 64
#define BBATCH  4096
#define IN_DIM  64
#define H_DIM   256

typedef __attribute__((ext_vector_type(8))) short short8;
typedef __attribute__((ext_vector_type(4))) short short4v;
typedef __attribute__((ext_vector_type(4))) float floatx4;

__device__ __forceinline__ unsigned short f2bf(float f) {
    unsigned int u = __builtin_bit_cast(unsigned int, f);
    return (unsigned short)((u + 0x8000u) >> 16);   // round-half-up, 0.5-ulp
}

// Transpose+cvt: W1 [M][64][256]->w1t [M][256][64] bf16 (blocks 0..255)
//                W2 [M][256][256]->w2t [M][256][256] bf16 (blocks 256..1279)
// Write phase: k-local is ALWAYS 0..63 (the staged tile is 64 rows); 8 threads
// cover one n-row's 64 k's, 32 rows per pass, 2 passes. Only the dst row
// stride differs between W1/W2. (R3 bug: j=tid&31 read LDS rows 64..255 OOB
// and clobbered neighboring kb blocks.)
__global__ __launch_bounds__(256) void prep_weights(const float* __restrict__ W1,
                                                    const float* __restrict__ W2,
                                                    unsigned short* __restrict__ w1t,
                                                    unsigned short* __restrict__ w2t) {
    __shared__ float lds[64][65];
    const int bid = blockIdx.x;
    const float* src;
    unsigned short* dst;
    int K, N, m, kb, nb;
    if (bid < 256) {
        m = bid >> 2; kb = 0; nb = bid & 3; K = IN_DIM; N = H_DIM;
        src = W1; dst = w1t;
    } else {
        int t = bid - 256;
        m = t >> 4; kb = (t >> 2) & 3; nb = t & 3; K = H_DIM; N = H_DIM;
        src = W2; dst = w2t;
    }
    const float* s = src + ((size_t)m * K + (size_t)kb * 64) * N + nb * 64;
    const int tid = threadIdx.x;
    const int r = tid >> 4, c4 = (tid & 15) * 4;
#pragma unroll
    for (int p = 0; p < 4; ++p) {
        int row = p * 16 + r;                      // k-local 0..63
        float4 v = *(const float4*)(s + (size_t)row * N + c4);
        lds[row][c4] = v.x; lds[row][c4 + 1] = v.y;
        lds[row][c4 + 2] = v.z; lds[row][c4 + 3] = v.w;
    }
    __syncthreads();
    unsigned short* dbase = dst + ((size_t)m * N + (size_t)nb * 64) * K + kb * 64;
    const int j = tid & 7;                         // k-chunk 0..7 (k = j*8..j*8+7)
#pragma unroll
    for (int it = 0; it < 2; ++it) {
        int n = it * 32 + (tid >> 3);              // n-local 0..63
        unsigned short tmp[8];
#pragma unroll
        for (int e = 0; e < 8; ++e) tmp[e] = f2bf(lds[j * 8 + e][n]);
        *(short8*)(dbase + (size_t)n * K + j * 8) = *(const short8*)tmp;
    }
}

// Fused 3-layer MLP. One WG per (model, 64-row batch tile); wave w owns
// h-columns {w*64 + c16*4 + nb}. h1 in 32 KB XOR-swizzled LDS; h2 in regs;
// phase-2 W2 B-frags double-buffered in registers (global-load prefetch).
__global__ __launch_bounds__(256, 3) void mlp_fused(
    const float* __restrict__ xs,
    const unsigned short* __restrict__ w1t,   // [M][H][IN] bf16
    const float* __restrict__ b1,
    const unsigned short* __restrict__ w2t,   // [M][H][H] bf16 (n-major)
    const float* __restrict__ b2,
    const float* __restrict__ w3,             // [M][H]
    const float* __restrict__ b3,             // [M]
    float* __restrict__ out)                  // [M][B]
{
    __shared__ unsigned short h1s[64 * 256];  // 32 KB
    float* red = (float*)h1s;                 // phase-3 overlay (behind barrier)

    const int bid = blockIdx.x;
    const int m   = bid >> 6;
    const int tb  = bid & 63;
    const int tid = threadIdx.x;
    const int w   = tid >> 6;
    const int lane = tid & 63;
    const int q   = lane >> 4;
    const int c16 = lane & 15;
    const int sw  = c16 & 7;

    // ---------------- Phase 1: h1 = relu(x @ W1 + b1) ----------------
    const float* xrow = xs + ((size_t)m * BBATCH + (size_t)tb * 64) * IN_DIM;
    const unsigned short* w1p = w1t + (size_t)m * (H_DIM * IN_DIM)
                                + (w * 64 + c16 * 4) * IN_DIM + q * 8;

    short8 ax[4][2];
#pragma unroll
    for (int rb = 0; rb < 4; ++rb)
#pragma unroll
        for (int kb = 0; kb < 2; ++kb) {
            const float* xp = xrow + (rb * 16 + c16) * IN_DIM + kb * 32 + q * 8;
            float4 v0 = *(const float4*)xp;
            float4 v1 = *(const float4*)(xp + 4);
            short8 a;
            a[0] = (short)f2bf(v0.x); a[1] = (short)f2bf(v0.y);
            a[2] = (short)f2bf(v0.z); a[3] = (short)f2bf(v0.w);
            a[4] = (short)f2bf(v1.x); a[5] = (short)f2bf(v1.y);
            a[6] = (short)f2bf(v1.z); a[7] = (short)f2bf(v1.w);
            ax[rb][kb] = a;
        }

    floatx4 acc[4][4];
#pragma unroll
    for (int rb = 0; rb < 4; ++rb)
#pragma unroll
        for (int nb = 0; nb < 4; ++nb)
            acc[rb][nb] = (floatx4){0.f, 0.f, 0.f, 0.f};

#pragma unroll
    for (int kb = 0; kb < 2; ++kb) {
        short8 bw[4];
#pragma unroll
        for (int nb = 0; nb < 4; ++nb)
            bw[nb] = *(const short8*)(w1p + nb * IN_DIM + kb * 32);
#pragma unroll
        for (int nb = 0; nb < 4; ++nb)
#pragma unroll
            for (int rb = 0; rb < 4; ++rb)
                acc[rb][nb] = __builtin_amdgcn_mfma_f32_16x16x32_bf16(
                    ax[rb][kb], bw[nb], acc[rb][nb], 0, 0, 0);
    }

    {   // epilogue: bias+relu+cvt, contiguous short4 per (rb,r), 16B-chunk XOR swizzle
        floatx4 b1v = *(const floatx4*)(b1 + m * H_DIM + w * 64 + c16 * 4);
#pragma unroll
        for (int rb = 0; rb < 4; ++rb)
#pragma unroll
            for (int r = 0; r < 4; ++r) {
                short4v t;
#pragma unroll
                for (int nb = 0; nb < 4; ++nb)
                    t[nb] = (short)f2bf(fmaxf(acc[rb][nb][r] + b1v[nb], 0.f));
                int row = rb * 16 + q * 4 + r;
                int chunk = (w * 8 + (c16 >> 1)) ^ (row & 7);
                *(short4v*)((char*)h1s + row * 512 + chunk * 16 + (c16 & 1) * 8) = t;
            }
    }
    __syncthreads();

    // ---------------- Phase 2: h2 = relu(h1 @ W2 + b2), B double-buffered ----------
#pragma unroll
    for (int rb = 0; rb < 4; ++rb)
#pragma unroll
        for (int nb = 0; nb < 4; ++nb)
            acc[rb][nb] = (floatx4){0.f, 0.f, 0.f, 0.f};

    const unsigned short* w2p = w2t + (size_t)m * (H_DIM * H_DIM)
                                + (w * 64 + c16 * 4) * H_DIM + q * 8;
    short8 bvA[4], bvB[4];
#pragma unroll
    for (int nb = 0; nb < 4; ++nb)
        bvA[nb] = *(const short8*)(w2p + nb * H_DIM);          // kb=0
#pragma unroll
    for (int kb = 0; kb < 8; ++kb) {
        short8* cur = (kb & 1) ? bvB : bvA;
        short8* nxt = (kb & 1) ? bvA : bvB;
        if (kb < 7) {
#pragma unroll
            for (int nb = 0; nb < 4; ++nb)
                nxt[nb] = *(const short8*)(w2p + nb * H_DIM + (kb + 1) * 32);
        }
        short8 av[4];
#pragma unroll
        for (int rb = 0; rb < 4; ++rb)
            av[rb] = *(const short8*)((char*)h1s + (rb * 16 + c16) * 512
                                      + (((kb * 4 + q) ^ sw) * 16));
#pragma unroll
        for (int nb = 0; nb < 4; ++nb)
#pragma unroll
            for (int rb = 0; rb < 4; ++rb)
                acc[rb][nb] = __builtin_amdgcn_mfma_f32_16x16x32_bf16(
                    av[rb], cur[nb], acc[rb][nb], 0, 0, 0);
    }

    // ---------------- Phase 3: out = h2 @ W3 + b3 (OUT=1), LDS tree --------------
    floatx4 b2v = *(const floatx4*)(b2 + m * H_DIM + w * 64 + c16 * 4);
    floatx4 w3v = *(const floatx4*)(w3 + m * H_DIM + w * 64 + c16 * 4);
    float p[4][4];
#pragma unroll
    for (int rb = 0; rb < 4; ++rb)
#pragma unroll
        for (int r = 0; r < 4; ++r) p[rb][r] = 0.f;
#pragma unroll
    for (int rb = 0; rb < 4; ++rb)
#pragma unroll
        for (int nb = 0; nb < 4; ++nb)
#pragma unroll
            for (int r = 0; r < 4; ++r) {
                float v = fmaxf(acc[rb][nb][r] + b2v[nb], 0.f);
                p[rb][r] += v * w3v[nb];
            }

    __syncthreads();                      // all h1s reads done -> overlay red
    const int unit = w * 16 + c16;        // 0..63 partial-sum slot
#pragma unroll
    for (int rb = 0; rb < 4; ++rb)
#pragma unroll
        for (int r = 0; r < 4; ++r)
            red[(rb * 16 + q * 4 + r) * 65 + unit] = p[rb][r];
    __syncthreads();
    if (tid < 64) {
        float s = b3[m];
#pragma unroll
        for (int u = 0; u < 64; ++u) s += red[tid * 65 + u];
        out[(size_t)m * BBATCH + tb * 64 + tid] = s;
    }
}

extern "C" void kernel_launch(void* const* d_in, const int* in_sizes, int n_in,
                              void* d_out, int out_size, void* d_ws, size_t ws_size,
                              hipStream_t stream) {
    const float* xs = (const float*)d_in[0];
    const float* W1 = (const float*)d_in[1];
    const float* b1 = (const float*)d_in[2];
    const float* W2 = (const float*)d_in[3];
    const float* b2 = (const float*)d_in[4];
    const float* W3 = (const float*)d_in[5];
    const float* b3 = (const float*)d_in[6];
    float* out = (float*)d_out;

    unsigned short* w1t = (unsigned short*)d_ws;                    // 2 MB
    unsigned short* w2t = w1t + (size_t)NMODELS * H_DIM * IN_DIM;   // 8.4 MB

    prep_weights<<<256 + NMODELS * 16, 256, 0, stream>>>(W1, W2, w1t, w2t);
    mlp_fused<<<NMODELS * (BBATCH / 64), 256, 0, stream>>>(xs, w1t, b1, w2t, b2, W3, b3, out);
}

// Round 6
// 181.161 us; speedup vs baseline: 1.1724x; 1.1724x over previous
//
#include <hip/hip_runtime.h>
#include <hip/hip_bf16.h>

#define NMODELS 64
#define BBATCH  4096
#define IN_DIM  64
#define H_DIM   256

typedef __attribute__((ext_vector_type(8))) short short8;
typedef __attribute__((ext_vector_type(4))) float floatx4;
typedef __attribute__((ext_vector_type(4))) unsigned int uint4v;
typedef __attribute__((ext_vector_type(2))) unsigned int uint2v;

__device__ __forceinline__ unsigned short f2bf(float f) {   // prep only
    unsigned int u = __builtin_bit_cast(unsigned int, f);
    return (unsigned short)((u + 0x8000u) >> 16);
}
// packed fp32x2 -> bf16x2 (v_cvt_pk_bf16_f32 on gfx950), RNE
__device__ __forceinline__ unsigned int pkbf(float a, float b) {
    __hip_bfloat162 h = __float22bfloat162_rn(make_float2(a, b));
    unsigned int u;
    __builtin_memcpy(&u, &h, 4);      // bit_cast rejects non-trivially-copyable type
    return u;
}

// Transpose+cvt: W1 [M][64][256]->w1t [M][256][64] bf16 (blocks 0..255)
//                W2 [M][256][256]->w2t [M][256][256] bf16 (blocks 256..1279)
__global__ __launch_bounds__(256) void prep_weights(const float* __restrict__ W1,
                                                    const float* __restrict__ W2,
                                                    unsigned short* __restrict__ w1t,
                                                    unsigned short* __restrict__ w2t) {
    __shared__ float lds[64][65];
    const int bid = blockIdx.x;
    const float* src;
    unsigned short* dst;
    int K, N, m, kb, nb;
    if (bid < 256) {
        m = bid >> 2; kb = 0; nb = bid & 3; K = IN_DIM; N = H_DIM;
        src = W1; dst = w1t;
    } else {
        int t = bid - 256;
        m = t >> 4; kb = (t >> 2) & 3; nb = t & 3; K = H_DIM; N = H_DIM;
        src = W2; dst = w2t;
    }
    const float* s = src + ((size_t)m * K + (size_t)kb * 64) * N + nb * 64;
    const int tid = threadIdx.x;
    const int r = tid >> 4, c4 = (tid & 15) * 4;
#pragma unroll
    for (int p = 0; p < 4; ++p) {
        int row = p * 16 + r;                      // k-local 0..63
        float4 v = *(const float4*)(s + (size_t)row * N + c4);
        lds[row][c4] = v.x; lds[row][c4 + 1] = v.y;
        lds[row][c4 + 2] = v.z; lds[row][c4 + 3] = v.w;
    }
    __syncthreads();
    unsigned short* dbase = dst + ((size_t)m * N + (size_t)nb * 64) * K + kb * 64;
    const int j = tid & 7;                         // k-chunk 0..7
#pragma unroll
    for (int it = 0; it < 2; ++it) {
        int n = it * 32 + (tid >> 3);              // n-local 0..63
        unsigned short tmp[8];
#pragma unroll
        for (int e = 0; e < 8; ++e) tmp[e] = f2bf(lds[j * 8 + e][n]);
        *(short8*)(dbase + (size_t)n * K + j * 8) = *(const short8*)tmp;
    }
}

// Fused 3-layer MLP, T=2 batch tiles per WG (shared weight fragments).
// Wave w owns h-cols {w*64 + c16*4 + nb}. Per tile: h1 in its own 32 KB
// XOR-swizzled LDS buffer; h2 in regs (128 AGPR across both tiles).
__global__ __launch_bounds__(256, 2) void mlp_fused(
    const float* __restrict__ xs,
    const unsigned short* __restrict__ w1t,   // [M][H][IN] bf16
    const float* __restrict__ b1,
    const unsigned short* __restrict__ w2t,   // [M][H][H] bf16 (n-major)
    const float* __restrict__ b2,
    const float* __restrict__ w3,             // [M][H]
    const float* __restrict__ b3,             // [M]
    float* __restrict__ out)                  // [M][B]
{
    __shared__ unsigned short h1s[2][64 * 256];   // 64 KB total
    float* red = (float*)h1s;                     // phase-3 overlay (behind barrier)

    const int bid = blockIdx.x;
    const int m     = bid >> 5;
    const int tile0 = (bid & 31) * 2;             // this WG: tiles tile0, tile0+1
    const int tid = threadIdx.x;
    const int w   = tid >> 6;
    const int lane = tid & 63;
    const int q   = lane >> 4;
    const int c16 = lane & 15;
    const int sw  = c16 & 7;

    // ---------------- Phase 1: h1[t] = relu(x[t] @ W1 + b1), t=0,1 ----------------
    const float* xrow0 = xs + ((size_t)m * BBATCH + (size_t)tile0 * 64) * IN_DIM;
    const unsigned short* w1p = w1t + (size_t)m * (H_DIM * IN_DIM)
                                + (w * 64 + c16 * 4) * IN_DIM + q * 8;

    short8 ax[2][4][2];
#pragma unroll
    for (int t = 0; t < 2; ++t)
#pragma unroll
        for (int rb = 0; rb < 4; ++rb)
#pragma unroll
            for (int kb = 0; kb < 2; ++kb) {
                const float* xp = xrow0 + (size_t)t * 64 * IN_DIM
                                  + (rb * 16 + c16) * IN_DIM + kb * 32 + q * 8;
                float4 v0 = *(const float4*)xp;
                float4 v1 = *(const float4*)(xp + 4);
                uint4v u;
                u[0] = pkbf(v0.x, v0.y); u[1] = pkbf(v0.z, v0.w);
                u[2] = pkbf(v1.x, v1.y); u[3] = pkbf(v1.z, v1.w);
                ax[t][rb][kb] = __builtin_bit_cast(short8, u);
            }

    floatx4 acc[2][4][4];
#pragma unroll
    for (int t = 0; t < 2; ++t)
#pragma unroll
        for (int rb = 0; rb < 4; ++rb)
#pragma unroll
            for (int nb = 0; nb < 4; ++nb)
                acc[t][rb][nb] = (floatx4){0.f, 0.f, 0.f, 0.f};

    {
        short8 bw[2][4];                          // shared across both tiles
#pragma unroll
        for (int kb = 0; kb < 2; ++kb)
#pragma unroll
            for (int nb = 0; nb < 4; ++nb)
                bw[kb][nb] = *(const short8*)(w1p + nb * IN_DIM + kb * 32);
#pragma unroll
        for (int t = 0; t < 2; ++t)
#pragma unroll
            for (int kb = 0; kb < 2; ++kb)
#pragma unroll
                for (int nb = 0; nb < 4; ++nb)
#pragma unroll
                    for (int rb = 0; rb < 4; ++rb)
                        acc[t][rb][nb] = __builtin_amdgcn_mfma_f32_16x16x32_bf16(
                            ax[t][rb][kb], bw[kb][nb], acc[t][rb][nb], 0, 0, 0);
    }

    {   // epilogue: bias+relu+packed cvt, 8B ds_write per (t,rb,r), 16B-chunk XOR swizzle
        floatx4 b1v = *(const floatx4*)(b1 + m * H_DIM + w * 64 + c16 * 4);
#pragma unroll
        for (int t = 0; t < 2; ++t)
#pragma unroll
            for (int rb = 0; rb < 4; ++rb)
#pragma unroll
                for (int r = 0; r < 4; ++r) {
                    float v0 = fmaxf(acc[t][rb][0][r] + b1v[0], 0.f);
                    float v1 = fmaxf(acc[t][rb][1][r] + b1v[1], 0.f);
                    float v2 = fmaxf(acc[t][rb][2][r] + b1v[2], 0.f);
                    float v3 = fmaxf(acc[t][rb][3][r] + b1v[3], 0.f);
                    uint2v u; u[0] = pkbf(v0, v1); u[1] = pkbf(v2, v3);
                    int row = rb * 16 + q * 4 + r;
                    int chunk = (w * 8 + (c16 >> 1)) ^ (row & 7);
                    *(uint2v*)((char*)&h1s[t][0] + row * 512 + chunk * 16 + (c16 & 1) * 8) = u;
                }
    }
    __syncthreads();

    // ---------------- Phase 2: h2[t] = relu(h1[t] @ W2 + b2); B shared ----------
#pragma unroll
    for (int t = 0; t < 2; ++t)
#pragma unroll
        for (int rb = 0; rb < 4; ++rb)
#pragma unroll
            for (int nb = 0; nb < 4; ++nb)
                acc[t][rb][nb] = (floatx4){0.f, 0.f, 0.f, 0.f};

    const unsigned short* w2p = w2t + (size_t)m * (H_DIM * H_DIM)
                                + (w * 64 + c16 * 4) * H_DIM + q * 8;
#pragma unroll
    for (int kb = 0; kb < 8; ++kb) {
        short8 bv[4], av[2][4];
#pragma unroll
        for (int nb = 0; nb < 4; ++nb)
            bv[nb] = *(const short8*)(w2p + nb * H_DIM + kb * 32);
#pragma unroll
        for (int t = 0; t < 2; ++t)
#pragma unroll
            for (int rb = 0; rb < 4; ++rb)
                av[t][rb] = *(const short8*)((char*)&h1s[t][0] + (rb * 16 + c16) * 512
                                             + (((kb * 4 + q) ^ sw) * 16));
#pragma unroll
        for (int nb = 0; nb < 4; ++nb)
#pragma unroll
            for (int t = 0; t < 2; ++t)
#pragma unroll
                for (int rb = 0; rb < 4; ++rb)
                    acc[t][rb][nb] = __builtin_amdgcn_mfma_f32_16x16x32_bf16(
                        av[t][rb], bv[nb], acc[t][rb][nb], 0, 0, 0);
    }

    // ---------------- Phase 3: out = h2 @ W3 + b3 (OUT=1), shfl reduce ----------
    floatx4 b2v = *(const floatx4*)(b2 + m * H_DIM + w * 64 + c16 * 4);
    floatx4 w3v = *(const floatx4*)(w3 + m * H_DIM + w * 64 + c16 * 4);
    float p[2][4][4];
#pragma unroll
    for (int t = 0; t < 2; ++t)
#pragma unroll
        for (int rb = 0; rb < 4; ++rb)
#pragma unroll
            for (int r = 0; r < 4; ++r) p[t][rb][r] = 0.f;
#pragma unroll
    for (int t = 0; t < 2; ++t)
#pragma unroll
        for (int rb = 0; rb < 4; ++rb)
#pragma unroll
            for (int nb = 0; nb < 4; ++nb)
#pragma unroll
                for (int r = 0; r < 4; ++r) {
                    float v = fmaxf(acc[t][rb][nb][r] + b2v[nb], 0.f);
                    p[t][rb][r] += v * w3v[nb];
                }
#pragma unroll
    for (int off = 1; off < 16; off <<= 1)
#pragma unroll
        for (int t = 0; t < 2; ++t)
#pragma unroll
            for (int rb = 0; rb < 4; ++rb)
#pragma unroll
                for (int r = 0; r < 4; ++r)
                    p[t][rb][r] += __shfl_xor(p[t][rb][r], off);

    __syncthreads();                   // all h1s reads done -> overlay red
    if (c16 == 0) {
#pragma unroll
        for (int t = 0; t < 2; ++t)
#pragma unroll
            for (int rb = 0; rb < 4; ++rb)
#pragma unroll
                for (int r = 0; r < 4; ++r)
                    red[t * 256 + w * 64 + rb * 16 + q * 4 + r] = p[t][rb][r];
    }
    __syncthreads();
    if (tid < 128) {
        int t = tid >> 6, rr = tid & 63;
        const float* rt = red + t * 256;
        float s = rt[rr] + rt[64 + rr] + rt[128 + rr] + rt[192 + rr] + b3[m];
        out[(size_t)m * BBATCH + (tile0 + t) * 64 + rr] = s;
    }
}

extern "C" void kernel_launch(void* const* d_in, const int* in_sizes, int n_in,
                              void* d_out, int out_size, void* d_ws, size_t ws_size,
                              hipStream_t stream) {
    const float* xs = (const float*)d_in[0];
    const float* W1 = (const float*)d_in[1];
    const float* b1 = (const float*)d_in[2];
    const float* W2 = (const float*)d_in[3];
    const float* b2 = (const float*)d_in[4];
    const float* W3 = (const float*)d_in[5];
    const float* b3 = (const float*)d_in[6];
    float* out = (float*)d_out;

    unsigned short* w1t = (unsigned short*)d_ws;                    // 2 MB
    unsigned short* w2t = w1t + (size_t)NMODELS * H_DIM * IN_DIM;   // 8.4 MB

    prep_weights<<<256 + NMODELS * 16, 256, 0, stream>>>(W1, W2, w1t, w2t);
    mlp_fused<<<NMODELS * (BBATCH / 128), 256, 0, stream>>>(xs, w1t, b1, w2t, b2, W3, b3, out);
}

// Round 7
// 180.000 us; speedup vs baseline: 1.1800x; 1.0064x over previous
//
#include <hip/hip_runtime.h>
#include <hip/hip_bf16.h>

#define NMODELS 64
#define BBATCH  4096
#define IN_DIM  64
#define H_DIM   256

typedef __attribute__((ext_vector_type(8))) short short8;
typedef __attribute__((ext_vector_type(4))) float floatx4;
typedef __attribute__((ext_vector_type(4))) unsigned int uint4v;
typedef __attribute__((ext_vector_type(2))) unsigned int uint2v;

__device__ __forceinline__ unsigned short f2bf(float f) {   // prep only
    unsigned int u = __builtin_bit_cast(unsigned int, f);
    return (unsigned short)((u + 0x8000u) >> 16);
}
// packed fp32x2 -> bf16x2 (v_cvt_pk_bf16_f32 on gfx950), RNE
__device__ __forceinline__ unsigned int pkbf(float a, float b) {
    __hip_bfloat162 h = __float22bfloat162_rn(make_float2(a, b));
    unsigned int u;
    __builtin_memcpy(&u, &h, 4);
    return u;
}

// Transpose+cvt: W1 [M][64][256]->w1t [M][256][64] bf16 (blocks 0..255)
//                W2 [M][256][256]->w2t [M][256][256] bf16 (blocks 256..1279)
__global__ __launch_bounds__(256) void prep_weights(const float* __restrict__ W1,
                                                    const float* __restrict__ W2,
                                                    unsigned short* __restrict__ w1t,
                                                    unsigned short* __restrict__ w2t) {
    __shared__ float lds[64][65];
    const int bid = blockIdx.x;
    const float* src;
    unsigned short* dst;
    int K, N, m, kb, nb;
    if (bid < 256) {
        m = bid >> 2; kb = 0; nb = bid & 3; K = IN_DIM; N = H_DIM;
        src = W1; dst = w1t;
    } else {
        int t = bid - 256;
        m = t >> 4; kb = (t >> 2) & 3; nb = t & 3; K = H_DIM; N = H_DIM;
        src = W2; dst = w2t;
    }
    const float* s = src + ((size_t)m * K + (size_t)kb * 64) * N + nb * 64;
    const int tid = threadIdx.x;
    const int r = tid >> 4, c4 = (tid & 15) * 4;
#pragma unroll
    for (int p = 0; p < 4; ++p) {
        int row = p * 16 + r;                      // k-local 0..63
        float4 v = *(const float4*)(s + (size_t)row * N + c4);
        lds[row][c4] = v.x; lds[row][c4 + 1] = v.y;
        lds[row][c4 + 2] = v.z; lds[row][c4 + 3] = v.w;
    }
    __syncthreads();
    unsigned short* dbase = dst + ((size_t)m * N + (size_t)nb * 64) * K + kb * 64;
    const int j = tid & 7;                         // k-chunk 0..7
#pragma unroll
    for (int it = 0; it < 2; ++it) {
        int n = it * 32 + (tid >> 3);              // n-local 0..63
        unsigned short tmp[8];
#pragma unroll
        for (int e = 0; e < 8; ++e) tmp[e] = f2bf(lds[j * 8 + e][n]);
        *(short8*)(dbase + (size_t)n * K + j * 8) = *(const short8*)tmp;
    }
}

// Fused 3-layer MLP, T=2 batch tiles per WG. Wave w owns h-cols
// {w*64 + c16*4 + nb}. h1 per tile in 32 KB XOR-swizzled LDS; h2 in regs.
// Phase-2 W2 B-frags: 3-slot rotating register prefetch (depth 2) — slots
// kb=0,1 issued before the barrier so L2 latency hides behind the epilogue
// and barrier drain; steady state keeps 2 rounds in flight. Reg budget:
// acc 128 AGPR + bv 48 + av 32 + addr/misc ~30 ≈ 240 <= 256 (2 waves/SIMD).
__global__ __launch_bounds__(256, 2) void mlp_fused(
    const float* __restrict__ xs,
    const unsigned short* __restrict__ w1t,   // [M][H][IN] bf16
    const float* __restrict__ b1,
    const unsigned short* __restrict__ w2t,   // [M][H][H] bf16 (n-major)
    const float* __restrict__ b2,
    const float* __restrict__ w3,             // [M][H]
    const float* __restrict__ b3,             // [M]
    float* __restrict__ out)                  // [M][B]
{
    __shared__ unsigned short h1s[2][64 * 256];   // 64 KB total
    float* red = (float*)h1s;                     // phase-3 overlay (behind barrier)

    const int bid = blockIdx.x;
    const int m     = bid >> 5;
    const int tile0 = (bid & 31) * 2;             // this WG: tiles tile0, tile0+1
    const int tid = threadIdx.x;
    const int w   = tid >> 6;
    const int lane = tid & 63;
    const int q   = lane >> 4;
    const int c16 = lane & 15;
    const int sw  = c16 & 7;

    // hoisted uniform-ish loads (latency hidden behind phase 1)
    floatx4 b1v = *(const floatx4*)(b1 + m * H_DIM + w * 64 + c16 * 4);
    floatx4 b2v = *(const floatx4*)(b2 + m * H_DIM + w * 64 + c16 * 4);
    floatx4 w3v = *(const floatx4*)(w3 + m * H_DIM + w * 64 + c16 * 4);
    const float b3v = b3[m];

    // ---------------- Phase 1: h1[t] = relu(x[t] @ W1 + b1), t=0,1 ----------------
    const float* xrow0 = xs + ((size_t)m * BBATCH + (size_t)tile0 * 64) * IN_DIM;
    const unsigned short* w1p = w1t + (size_t)m * (H_DIM * IN_DIM)
                                + (w * 64 + c16 * 4) * IN_DIM + q * 8;
    const unsigned short* w2p = w2t + (size_t)m * (H_DIM * H_DIM)
                                + (w * 64 + c16 * 4) * H_DIM + q * 8;

    short8 ax[2][4][2];
#pragma unroll
    for (int t = 0; t < 2; ++t)
#pragma unroll
        for (int rb = 0; rb < 4; ++rb)
#pragma unroll
            for (int kb = 0; kb < 2; ++kb) {
                const float* xp = xrow0 + (size_t)t * 64 * IN_DIM
                                  + (rb * 16 + c16) * IN_DIM + kb * 32 + q * 8;
                float4 v0 = *(const float4*)xp;
                float4 v1 = *(const float4*)(xp + 4);
                uint4v u;
                u[0] = pkbf(v0.x, v0.y); u[1] = pkbf(v0.z, v0.w);
                u[2] = pkbf(v1.x, v1.y); u[3] = pkbf(v1.z, v1.w);
                ax[t][rb][kb] = __builtin_bit_cast(short8, u);
            }

    floatx4 acc[2][4][4];
#pragma unroll
    for (int t = 0; t < 2; ++t)
#pragma unroll
        for (int rb = 0; rb < 4; ++rb)
#pragma unroll
            for (int nb = 0; nb < 4; ++nb)
                acc[t][rb][nb] = (floatx4){0.f, 0.f, 0.f, 0.f};

    {
        short8 bw[2][4];                          // shared across both tiles
#pragma unroll
        for (int kb = 0; kb < 2; ++kb)
#pragma unroll
            for (int nb = 0; nb < 4; ++nb)
                bw[kb][nb] = *(const short8*)(w1p + nb * IN_DIM + kb * 32);
#pragma unroll
        for (int t = 0; t < 2; ++t)
#pragma unroll
            for (int kb = 0; kb < 2; ++kb)
#pragma unroll
                for (int nb = 0; nb < 4; ++nb)
#pragma unroll
                    for (int rb = 0; rb < 4; ++rb)
                        acc[t][rb][nb] = __builtin_amdgcn_mfma_f32_16x16x32_bf16(
                            ax[t][rb][kb], bw[kb][nb], acc[t][rb][nb], 0, 0, 0);
    }

    // Prefetch phase-2 B slots kb=0,1 NOW (h1-independent): latency overlaps
    // the epilogue cvt/ds_write and the barrier drain.
    short8 bv[3][4];
#pragma unroll
    for (int nb = 0; nb < 4; ++nb) bv[0][nb] = *(const short8*)(w2p + nb * H_DIM + 0 * 32);
#pragma unroll
    for (int nb = 0; nb < 4; ++nb) bv[1][nb] = *(const short8*)(w2p + nb * H_DIM + 1 * 32);

    {   // epilogue: bias+relu+packed cvt, 8B ds_write per (t,rb,r), 16B-chunk XOR swizzle
#pragma unroll
        for (int t = 0; t < 2; ++t)
#pragma unroll
            for (int rb = 0; rb < 4; ++rb)
#pragma unroll
                for (int r = 0; r < 4; ++r) {
                    float v0 = fmaxf(acc[t][rb][0][r] + b1v[0], 0.f);
                    float v1 = fmaxf(acc[t][rb][1][r] + b1v[1], 0.f);
                    float v2 = fmaxf(acc[t][rb][2][r] + b1v[2], 0.f);
                    float v3 = fmaxf(acc[t][rb][3][r] + b1v[3], 0.f);
                    uint2v u; u[0] = pkbf(v0, v1); u[1] = pkbf(v2, v3);
                    int row = rb * 16 + q * 4 + r;
                    int chunk = (w * 8 + (c16 >> 1)) ^ (row & 7);
                    *(uint2v*)((char*)&h1s[t][0] + row * 512 + chunk * 16 + (c16 & 1) * 8) = u;
                }
    }
    __syncthreads();

    // ---------------- Phase 2: h2[t] = relu(h1[t] @ W2 + b2); pipelined B ----------
#pragma unroll
    for (int t = 0; t < 2; ++t)
#pragma unroll
        for (int rb = 0; rb < 4; ++rb)
#pragma unroll
            for (int nb = 0; nb < 4; ++nb)
                acc[t][rb][nb] = (floatx4){0.f, 0.f, 0.f, 0.f};

#pragma unroll
    for (int kb = 0; kb < 8; ++kb) {
        const int cur = kb % 3;
        const int pre = (kb + 2) % 3;
        if (kb < 6) {                             // keep depth-2 in flight
#pragma unroll
            for (int nb = 0; nb < 4; ++nb)
                bv[pre][nb] = *(const short8*)(w2p + nb * H_DIM + (kb + 2) * 32);
        }
        short8 av[2][4];
#pragma unroll
        for (int t = 0; t < 2; ++t)
#pragma unroll
            for (int rb = 0; rb < 4; ++rb)
                av[t][rb] = *(const short8*)((char*)&h1s[t][0] + (rb * 16 + c16) * 512
                                             + (((kb * 4 + q) ^ sw) * 16));
#pragma unroll
        for (int nb = 0; nb < 4; ++nb)
#pragma unroll
            for (int t = 0; t < 2; ++t)
#pragma unroll
                for (int rb = 0; rb < 4; ++rb)
                    acc[t][rb][nb] = __builtin_amdgcn_mfma_f32_16x16x32_bf16(
                        av[t][rb], bv[cur][nb], acc[t][rb][nb], 0, 0, 0);
    }

    // ---------------- Phase 3: out = h2 @ W3 + b3 (OUT=1), shfl reduce ----------
    float p[2][4][4];
#pragma unroll
    for (int t = 0; t < 2; ++t)
#pragma unroll
        for (int rb = 0; rb < 4; ++rb)
#pragma unroll
            for (int r = 0; r < 4; ++r) p[t][rb][r] = 0.f;
#pragma unroll
    for (int t = 0; t < 2; ++t)
#pragma unroll
        for (int rb = 0; rb < 4; ++rb)
#pragma unroll
            for (int nb = 0; nb < 4; ++nb)
#pragma unroll
                for (int r = 0; r < 4; ++r) {
                    float v = fmaxf(acc[t][rb][nb][r] + b2v[nb], 0.f);
                    p[t][rb][r] += v * w3v[nb];
                }
#pragma unroll
    for (int off = 1; off < 16; off <<= 1)
#pragma unroll
        for (int t = 0; t < 2; ++t)
#pragma unroll
            for (int rb = 0; rb < 4; ++rb)
#pragma unroll
                for (int r = 0; r < 4; ++r)
                    p[t][rb][r] += __shfl_xor(p[t][rb][r], off);

    __syncthreads();                   // all h1s reads done -> overlay red
    if (c16 == 0) {
#pragma unroll
        for (int t = 0; t < 2; ++t)
#pragma unroll
            for (int rb = 0; rb < 4; ++rb)
#pragma unroll
                for (int r = 0; r < 4; ++r)
                    red[t * 256 + w * 64 + rb * 16 + q * 4 + r] = p[t][rb][r];
    }
    __syncthreads();
    if (tid < 128) {
        int t = tid >> 6, rr = tid & 63;
        const float* rt = red + t * 256;
        float s = rt[rr] + rt[64 + rr] + rt[128 + rr] + rt[192 + rr] + b3v;
        out[(size_t)m * BBATCH + (tile0 + t) * 64 + rr] = s;
    }
}

extern "C" void kernel_launch(void* const* d_in, const int* in_sizes, int n_in,
                              void* d_out, int out_size, void* d_ws, size_t ws_size,
                              hipStream_t stream) {
    const float* xs = (const float*)d_in[0];
    const float* W1 = (const float*)d_in[1];
    const float* b1 = (const float*)d_in[2];
    const float* W2 = (const float*)d_in[3];
    const float* b2 = (const float*)d_in[4];
    const float* W3 = (const float*)d_in[5];
    const float* b3 = (const float*)d_in[6];
    float* out = (float*)d_out;

    unsigned short* w1t = (unsigned short*)d_ws;                    // 2 MB
    unsigned short* w2t = w1t + (size_t)NMODELS * H_DIM * IN_DIM;   // 8.4 MB

    prep_weights<<<256 + NMODELS * 16, 256, 0, stream>>>(W1, W2, w1t, w2t);
    mlp_fused<<<NMODELS * (BBATCH / 128), 256, 0, stream>>>(xs, w1t, b1, w2t, b2, W3, b3, out);
}